// Round 7
// baseline (537.696 us; speedup 1.0000x reference)
//
#include <hip/hip_runtime.h>
#include <math.h>

#define ALPHA_C 0.1f
#define EPB 4096  // edges per block in binning kernels (16 per thread)

typedef __attribute__((ext_vector_type(4))) float f32x4;
typedef __attribute__((ext_vector_type(2))) float f32x2;
typedef __attribute__((ext_vector_type(8))) short bf16x8;

__device__ __forceinline__ float readlane_f(float v, int l) {
    return __int_as_float(__builtin_amdgcn_readlane(__float_as_int(v), l));
}

__device__ __forceinline__ unsigned short bf16_rtne(float f) {
    unsigned u = __float_as_uint(f);
    unsigned r = (u + 0x7FFFu + ((u >> 16) & 1u)) >> 16;
    return (unsigned short)r;
}

// ---- range histogram: 64 coarse bins (no 100k-wide random atomics) ----
__global__ void k_rhist(const int* __restrict__ col, int E, int span,
                        int* __restrict__ rangecount) {
    __shared__ int l[64];
    int tid = threadIdx.x;
    if (tid < 64) l[tid] = 0;
    __syncthreads();
    int base = blockIdx.x * EPB;
#pragma unroll
    for (int it = 0; it < 16; ++it) {
        int e = base + it * 256 + tid;
        if (e < E) atomicAdd(&l[(unsigned)col[e] / (unsigned)span], 1);
    }
    __syncthreads();
    if (tid < 64 && l[tid]) atomicAdd(&rangecount[tid], l[tid]);
}

__global__ void k_rscan(const int* __restrict__ rangecount,
                        int* __restrict__ rangeoffs, int E) {
    __shared__ int s[64];
    int tid = threadIdx.x;  // one 64-thread block
    int v = rangecount[tid];
    s[tid] = v;
    __syncthreads();
    for (int d = 1; d < 64; d <<= 1) {
        int t = (tid >= d) ? s[tid - d] : 0;
        __syncthreads();
        s[tid] += t;
        __syncthreads();
    }
    rangeoffs[tid] = s[tid] - v;
    if (tid == 63) rangeoffs[64] = E;
}

// ---- phase A: bin edges into 64 destination ranges (write-amp ~1x) ----
__global__ void k_binA(const int* __restrict__ row, const int* __restrict__ col,
                       const int* __restrict__ rangeoffs, int* __restrict__ gcur,
                       uint2* __restrict__ staged, int E, int span) {
    __shared__ int lrun[64];
    int tid = threadIdx.x;
    int base = blockIdx.x * EPB;
    if (tid < 64) lrun[tid] = 0;
    __syncthreads();
#pragma unroll
    for (int it = 0; it < 16; ++it) {
        int e = base + it * 256 + tid;
        if (e < E) atomicAdd(&lrun[(unsigned)col[e] / (unsigned)span], 1);
    }
    __syncthreads();
    if (tid < 64) {
        int cnt = lrun[tid];
        int gb = cnt ? atomicAdd(&gcur[tid], cnt) : 0;
        lrun[tid] = rangeoffs[tid] + gb;  // absolute staged cursor for block+range
    }
    __syncthreads();
#pragma unroll
    for (int it = 0; it < 16; ++it) {
        int e = base + it * 256 + tid;
        if (e < E) {
            int c = col[e];
            int r = (unsigned)c / (unsigned)span;
            int pos = atomicAdd(&lrun[r], 1);
            staged[pos] = make_uint2((unsigned)c, (unsigned)row[e]);
        }
    }
}

// ---- phase B: per range: LDS node-hist -> in-block scan -> offs/dinv -> place ----
__global__ void k_binB(const uint2* __restrict__ staged, const int* __restrict__ rangeoffs,
                       int* __restrict__ offs, float* __restrict__ dinv,
                       int* __restrict__ srcarr, int N, int span) {
    __shared__ int lcnt[1600];
    __shared__ int partial[256];
    int r = blockIdx.x;
    int tid = threadIdx.x;
    int nstart = r * span;
    if (nstart >= N) return;
    int nend = nstart + span; if (nend > N) nend = N;
    int cnt = nend - nstart;
    int estart = rangeoffs[r], eend = rangeoffs[r + 1];
    for (int t = tid; t < cnt; t += 256) lcnt[t] = 0;
    __syncthreads();
    for (int e = estart + tid; e < eend; e += 256)
        atomicAdd(&lcnt[(int)staged[e].x - nstart], 1);
    __syncthreads();
    int chunk = (cnt + 255) / 256;
    int c0 = tid * chunk; if (c0 > cnt) c0 = cnt;
    int c1 = c0 + chunk;  if (c1 > cnt) c1 = cnt;
    int sum = 0;
    for (int t = c0; t < c1; ++t) sum += lcnt[t];
    partial[tid] = sum;
    __syncthreads();
    for (int d = 1; d < 256; d <<= 1) {
        int t = (tid >= d) ? partial[tid - d] : 0;
        __syncthreads();
        partial[tid] += t;
        __syncthreads();
    }
    int run = estart + partial[tid] - sum;
    for (int t = c0; t < c1; ++t) {
        int c = lcnt[t];
        lcnt[t] = run;
        offs[nstart + t] = run;
        dinv[nstart + t] = rsqrtf(1.0f + (float)c);
        run += c;
    }
    if (nend == N && tid == 0) offs[N] = eend;
    __syncthreads();
    for (int e = estart + tid; e < eend; e += 256) {
        uint2 cr = staged[e];
        int idx = atomicAdd(&lcnt[(int)cr.x - nstart], 1);
        srcarr[idx] = (int)cr.y;
    }
}

// -- input: h0b = bf16(relu(x @ W_in + b_in));  g = bf16(dinv * relu(...)) --
__global__ void k_in(const float* __restrict__ x, const float* __restrict__ Win,
                     const float* __restrict__ bin, const float* __restrict__ dinv,
                     unsigned short* __restrict__ h0b, unsigned short* __restrict__ g,
                     int N) {
    int lane = threadIdx.x & 63;
    int wave = (blockIdx.x * blockDim.x + threadIdx.x) >> 6;
    int nwaves = (gridDim.x * blockDim.x) >> 6;
    float wreg[17];
#pragma unroll
    for (int k = 0; k < 17; ++k) wreg[k] = Win[k * 64 + lane];
    float breg = bin[lane];
    for (int i = wave; i < N; i += nwaves) {
        float xv = (lane < 17) ? x[i * 17 + lane] : 0.0f;
        float acc = breg;
#pragma unroll
        for (int k = 0; k < 17; ++k) acc += readlane_f(xv, k) * wreg[k];
        float r = fmaxf(acc, 0.0f);
        h0b[(size_t)i * 64 + lane] = bf16_rtne(r);
        g[(size_t)i * 64 + lane] = bf16_rtne(dinv[i] * r);
    }
}

// ---- fused gather+mix, one 16-node tile per wave, half-wave per node ----
//   A[i] = dinv[i]*(sum_e g[src] + g[i])            (gathered into LDS, f32)
//   out  = relu( c1*A + mfma([A|h0b] @ [bW1 ; bW2 + c2*I]) )
// c2*I folded into the B-fragment diagonal -> no epilogue h0 read.
template <bool WRITE_G>
__global__ void k_gmix(const unsigned int* __restrict__ gp,
                       const unsigned int* __restrict__ h0b,  // bf16 pairs
                       const float* __restrict__ W1, const float* __restrict__ W2,
                       const float* __restrict__ dinv, const int* __restrict__ offs,
                       const int* __restrict__ srcarr, float beta,
                       float* __restrict__ of32, unsigned short* __restrict__ og16,
                       int N, int ntiles) {
    __shared__ float atile_s[4][16][68];
    int lane = threadIdx.x & 63;
    int wv = threadIdx.x >> 6;
    float (*atile)[68] = atile_s[wv];      // wave-private
    int p = lane & 31, s = lane >> 5;
    int t = (blockIdx.x * blockDim.x + threadIdx.x) >> 6;  // one tile per wave
    float c1 = (1.0f - beta) * (1.0f - ALPHA_C);
    float c2 = (1.0f - beta) * ALPHA_C;

    bf16x8 bfrag[4][4];  // [col-tile][k-step]; beta*W (+c2*I on the W2 half)
#pragma unroll
    for (int c = 0; c < 4; ++c) {
#pragma unroll
        for (int ks = 0; ks < 4; ++ks) {
            int n = c * 16 + (lane & 15);
            int kb = ks * 32 + (lane >> 4) * 8;
            bf16x8 f;
#pragma unroll
            for (int j = 0; j < 8; ++j) {
                int k = kb + j;
                float w = (k < 64)
                    ? beta * W1[k * 64 + n]
                    : beta * W2[(k - 64) * 64 + n] + (((k - 64) == n) ? c2 : 0.0f);
                f[j] = (short)bf16_rtne(w);
            }
            bfrag[c][ks] = f;
        }
    }

    if (t >= ntiles) return;

    // ---- gather: each half-wave owns node t*16 + 2*ii + s ----
    for (int ii = 0; ii < 8; ++ii) {
        int i = t * 16 + 2 * ii + s; if (i >= N) i = N - 1;
        int e0 = offs[i], e1 = offs[i + 1];
        float a0 = 0.0f, a1 = 0.0f;
        for (int base = e0; base < e1; base += 8) {
            int idx[8];
            unsigned v[8];
#pragma unroll
            for (int u = 0; u < 8; ++u) {
                int ee = base + u;
                idx[u] = srcarr[ee < e1 ? ee : e1 - 1];
            }
#pragma unroll
            for (int u = 0; u < 8; ++u) v[u] = gp[(size_t)idx[u] * 32 + p];
#pragma unroll
            for (int u = 0; u < 8; ++u) {
                bool ok = (base + u < e1);
                a0 += ok ? __uint_as_float(v[u] << 16) : 0.0f;
                a1 += ok ? __uint_as_float(v[u] & 0xFFFF0000u) : 0.0f;
            }
        }
        unsigned sv = gp[(size_t)i * 32 + p];  // self-loop term
        a0 += __uint_as_float(sv << 16);
        a1 += __uint_as_float(sv & 0xFFFF0000u);
        float di = dinv[i];
        int r16 = 2 * ii + s;
        f32x2 w = {di * a0, di * a1};
        *(f32x2*)&atile[r16][2 * p] = w;
        if (p == 0) atile[r16][66] = di;   // stash dinv for the epilogue
    }

    // ---- MFMA: [A(LDS f32) | h0b(bf16)] @ bfrag ----
    int rl = lane & 15;
    int koff = (lane >> 4) * 8;
    int grow = t * 16 + rl; if (grow >= N) grow = N - 1;
    f32x4 acc[4];
#pragma unroll
    for (int c = 0; c < 4; ++c) acc[c] = (f32x4){0.f, 0.f, 0.f, 0.f};
#pragma unroll
    for (int ks = 0; ks < 4; ++ks) {
        bf16x8 af;
        if (ks < 2) {
            const float* sp = &atile[rl][ks * 32 + koff];
            f32x4 lo = *(const f32x4*)sp;
            f32x4 hi = *(const f32x4*)(sp + 4);
#pragma unroll
            for (int j = 0; j < 4; ++j) af[j] = (short)bf16_rtne(lo[j]);
#pragma unroll
            for (int j = 0; j < 4; ++j) af[4 + j] = (short)bf16_rtne(hi[j]);
        } else {
            af = *(const bf16x8*)&h0b[((size_t)grow * 64 + (ks - 2) * 32 + koff) >> 1];
        }
#pragma unroll
        for (int c = 0; c < 4; ++c)
            acc[c] = __builtin_amdgcn_mfma_f32_16x16x32_bf16(af, bfrag[c][ks], acc[c], 0, 0, 0);
    }

    // ---- epilogue: f32 residual + relu ----
#pragma unroll
    for (int c = 0; c < 4; ++c) {
        int col = c * 16 + rl;
#pragma unroll
        for (int q = 0; q < 4; ++q) {
            int row16 = (lane >> 4) * 4 + q;
            int gr = t * 16 + row16;
            if (gr < N) {
                float v = c1 * atile[row16][col] + acc[c][q];
                float rr = fmaxf(v, 0.0f);
                size_t o = (size_t)gr * 64 + col;
                if (WRITE_G) og16[o] = bf16_rtne(atile[row16][66] * rr);
                else         of32[o] = rr;
            }
        }
    }
}

// ---------------- head: log_softmax(h @ W_out + b_out) ----------------
__global__ void k_out(const float* __restrict__ h, const float* __restrict__ Wout,
                      const float* __restrict__ bout, float* __restrict__ out, int N) {
    int lane = threadIdx.x & 63;
    int wave = (blockIdx.x * blockDim.x + threadIdx.x) >> 6;
    int nwaves = (gridDim.x * blockDim.x) >> 6;
    float w0 = Wout[lane * 2 + 0], w1 = Wout[lane * 2 + 1];
    float b0 = bout[0], b1 = bout[1];
    for (int i = wave; i < N; i += nwaves) {
        float hv = h[(size_t)i * 64 + lane];
        float p0 = hv * w0, p1 = hv * w1;
#pragma unroll
        for (int d = 32; d > 0; d >>= 1) {
            p0 += __shfl_xor(p0, d, 64);
            p1 += __shfl_xor(p1, d, 64);
        }
        if (lane == 0) {
            float c0 = p0 + b0, c1 = p1 + b1;
            float m = fmaxf(c0, c1);
            float lse = m + logf(expf(c0 - m) + expf(c1 - m));
            out[(size_t)i * 2 + 0] = c0 - lse;
            out[(size_t)i * 2 + 1] = c1 - lse;
        }
    }
}

extern "C" void kernel_launch(void* const* d_in, const int* in_sizes, int n_in,
                              void* d_out, int out_size, void* d_ws, size_t ws_size,
                              hipStream_t stream) {
    const float* x    = (const float*)d_in[0];
    const int*   ei   = (const int*)d_in[1];
    const float* Win  = (const float*)d_in[2];
    const float* bin  = (const float*)d_in[3];
    const float* W1   = (const float*)d_in[4];
    const float* W2   = (const float*)d_in[5];
    const float* Wout = (const float*)d_in[6];
    const float* bout = (const float*)d_in[7];
    float* out = (float*)d_out;

    const int N = in_sizes[0] / 17;
    const int E = in_sizes[1] / 2;
    const int* rowp = ei;
    const int* colp = ei + E;
    const int span = (N + 63) / 64;   // <= 1600 assumed (N <= 102400)

    char* p = (char*)d_ws;
    auto alloc = [&](size_t bytes) -> char* {
        char* r = p;
        p += (bytes + 255) & ~(size_t)255;
        return r;
    };
    int*   offs   = (int*)alloc((size_t)(N + 1) * sizeof(int));
    float* dinv   = (float*)alloc((size_t)N * sizeof(float));
    int*   rc_gc  = (int*)alloc(128 * sizeof(int));
    int*   roffs  = (int*)alloc(65 * sizeof(int));
    int*   srcarr = (int*)alloc((size_t)E * sizeof(int));
    size_t gbytes  = (size_t)N * 64 * sizeof(unsigned short);
    size_t stbytes = (size_t)E * sizeof(uint2);
    char*  stg    = alloc(stbytes > gbytes ? stbytes : gbytes);  // staged, later gB
    unsigned short* h0b  = (unsigned short*)alloc(gbytes);
    float*          hfin = (float*)alloc((size_t)N * 64 * sizeof(float));
    unsigned short* gA   = (unsigned short*)alloc(gbytes);
    uint2*          staged = (uint2*)stg;
    unsigned short* gB     = (unsigned short*)stg;  // staged dead after binB

    int* rangecount = rc_gc;
    int* gcur       = rc_gc + 64;
    hipMemsetAsync(rc_gc, 0, 128 * sizeof(int), stream);

    const int TB = 256;
    const int nbA = (E + EPB - 1) / EPB;

    k_rhist<<<nbA, TB, 0, stream>>>(colp, E, span, rangecount);
    k_rscan<<<1, 64, 0, stream>>>(rangecount, roffs, E);
    k_binA<<<nbA, TB, 0, stream>>>(rowp, colp, roffs, gcur, staged, E, span);
    k_binB<<<64, TB, 0, stream>>>(staged, roffs, offs, dinv, srcarr, N, span);

    k_in<<<2048, TB, 0, stream>>>(x, Win, bin, dinv, h0b, gA, N);

    const int ntiles = (N + 15) >> 4;
    const int nbG = (ntiles + 3) / 4;   // one tile per wave, 4 waves per block

    // ping-pong g buffers: L0 gA->gB, L1 gB->gA, L2 gA->gB, L3 gB->hfin(f32)
    for (int l = 0; l < 4; ++l) {
        float beta = logf(0.5f / (float)(l + 1) + 1.0f);
        const unsigned short* gin  = (l & 1) ? gB : gA;
        unsigned short*       gout = (l & 1) ? gA : gB;
        if (l < 3)
            k_gmix<true><<<nbG, TB, 0, stream>>>((const unsigned int*)gin,
                                                 (const unsigned int*)h0b,
                                                 W1 + (size_t)l * 4096, W2 + (size_t)l * 4096,
                                                 dinv, offs, srcarr, beta,
                                                 nullptr, gout, N, ntiles);
        else
            k_gmix<false><<<nbG, TB, 0, stream>>>((const unsigned int*)gin,
                                                  (const unsigned int*)h0b,
                                                  W1 + (size_t)l * 4096, W2 + (size_t)l * 4096,
                                                  dinv, offs, srcarr, beta,
                                                  hfin, nullptr, N, ntiles);
    }
    k_out<<<1024, TB, 0, stream>>>(hfin, Wout, bout, out, N);
}